// Round 1
// baseline (230.738 us; speedup 1.0000x reference)
//
#include <hip/hip_runtime.h>
#include <math.h>

#define NPAIR   2
#define CDIM    64
#define NKP     400
#define NPAD    448
#define HW      65536
#define IMGW    256
#define MCHUNK  128
#define MB_PER_P 512   /* HW / MCHUNK */
#define NCHUNK  64

/* ws layout (floats):
   [0, NPAIR*CDIM*NPAD)                : normalized tgt desc [p][c][n]
   [WS_PART, +NPAIR*MB_PER_P*NKP*4)    : partials [p][mb][n][{max,sum,U,V}] */
#define WS_PART (NPAIR*CDIM*NPAD)

__global__ __launch_bounds__(64) void prep_kernel(
    const float* __restrict__ ks, const float* __restrict__ kd,
    const int* __restrict__ tgt_ids, const int* __restrict__ src_ids,
    float* __restrict__ ws, float* __restrict__ out)
{
    int n = blockIdx.x;        // 0..447
    int p = blockIdx.y;        // 0..1
    int c = threadIdx.x;       // 0..63
    int tgt = tgt_ids[p];
    float val = (n < NKP) ? kd[(tgt*CDIM + c)*NKP + n] : 0.0f;
    float ss = val*val;
    #pragma unroll
    for (int off = 1; off < 64; off <<= 1) ss += __shfl_xor(ss, off);
    float inv = 1.0f / fmaxf(sqrtf(ss), 1e-12f);
    ws[(p*CDIM + c)*NPAD + n] = val * inv;
    if (c == 0 && n < NKP) out[NPAIR*NKP*2 + p*NKP + n] = ks[tgt*NKP + n];
    if (c == 0 && n == 0) {
        out[NPAIR*NKP*3 + p]         = (float)tgt;
        out[NPAIR*NKP*3 + NPAIR + p] = (float)src_ids[p];
    }
}

__global__ __launch_bounds__(256) void match_kernel(
    const float* __restrict__ dd, const int* __restrict__ src_ids,
    float* __restrict__ ws)
{
    __shared__ float src_s[CDIM][MCHUNK];   // 32 KB
    __shared__ float tgt_s[CDIM][NCHUNK];   // 16 KB
    __shared__ float invn_s[MCHUNK];        // 0.5 KB

    int mb = blockIdx.x;       // 0..511
    int p  = blockIdx.y;       // 0..1
    int t  = threadIdx.x;      // 0..255
    int src = src_ids[p];

    const float* tgtn = ws;                                  // [p][c][NPAD]
    float* part = ws + WS_PART;                              // [p][mb][n][4]
    const float* plane = dd + (size_t)src*CDIM*HW + (size_t)mb*MCHUNK;

    // stage src tile [64][128]
    #pragma unroll
    for (int i = 0; i < 8; ++i) {
        int f4 = t + i*256;
        int c = f4 >> 5, col = (f4 & 31) << 2;
        *(float4*)&src_s[c][col] = *(const float4*)&plane[(size_t)c*HW + col];
    }
    __syncthreads();

    // per-m inverse norm, folded with 1/temp = 100
    if (t < MCHUNK) {
        float s = 0.0f;
        #pragma unroll 8
        for (int c = 0; c < CDIM; ++c) { float x = src_s[c][t]; s = fmaf(x, x, s); }
        invn_s[t] = 100.0f / fmaxf(sqrtf(s), 1e-12f);
    }
    __syncthreads();

    int mg = t & 31, ng = t >> 5;
    int m0 = mg << 2, n0 = ng << 3;
    float inv[4];
    #pragma unroll
    for (int j = 0; j < 4; ++j) inv[j] = invn_s[m0 + j];
    float ubase = (float)((mb & 1)*MCHUNK + m0);
    float vrow  = (float)(mb >> 1);
    float* pblk = part + (size_t)(p*MB_PER_P + mb)*NKP*4;

    for (int nc = 0; nc < NPAD; nc += NCHUNK) {
        __syncthreads();   // protect tgt_s from previous iteration's readers
        #pragma unroll
        for (int i = 0; i < 4; ++i) {
            int f4 = t + i*256;
            int c = f4 >> 4, nn = (f4 & 15) << 2;
            *(float4*)&tgt_s[c][nn] = *(const float4*)&tgtn[(p*CDIM + c)*NPAD + nc + nn];
        }
        __syncthreads();

        float acc[8][4] = {};
        #pragma unroll 4
        for (int c = 0; c < CDIM; ++c) {
            float4 s4 = *(const float4*)&src_s[c][m0];
            float4 ta = *(const float4*)&tgt_s[c][n0];
            float4 tb = *(const float4*)&tgt_s[c][n0 + 4];
            float tv[8] = {ta.x, ta.y, ta.z, ta.w, tb.x, tb.y, tb.z, tb.w};
            #pragma unroll
            for (int r = 0; r < 8; ++r) {
                acc[r][0] = fmaf(tv[r], s4.x, acc[r][0]);
                acc[r][1] = fmaf(tv[r], s4.y, acc[r][1]);
                acc[r][2] = fmaf(tv[r], s4.z, acc[r][2]);
                acc[r][3] = fmaf(tv[r], s4.w, acc[r][3]);
            }
        }

        // fused online-softmax partials per n-row (reduce over 32 m-group lanes)
        #pragma unroll
        for (int r = 0; r < 8; ++r) {
            int n = nc + n0 + r;
            float L0 = acc[r][0]*inv[0], L1 = acc[r][1]*inv[1];
            float L2 = acc[r][2]*inv[2], L3 = acc[r][3]*inv[3];
            float mx = fmaxf(fmaxf(L0, L1), fmaxf(L2, L3));
            #pragma unroll
            for (int off = 1; off < 32; off <<= 1) mx = fmaxf(mx, __shfl_xor(mx, off));
            float e0 = __expf(L0 - mx), e1 = __expf(L1 - mx);
            float e2 = __expf(L2 - mx), e3 = __expf(L3 - mx);
            float s = e0 + e1 + e2 + e3;
            float u = e0*ubase + e1*(ubase+1.0f) + e2*(ubase+2.0f) + e3*(ubase+3.0f);
            #pragma unroll
            for (int off = 1; off < 32; off <<= 1) {
                s += __shfl_xor(s, off);
                u += __shfl_xor(u, off);
            }
            if (mg == 0 && n < NKP) {
                float4 q = make_float4(mx, s, u, vrow*s);
                *(float4*)&pblk[n*4] = q;
            }
        }
    }
}

__global__ __launch_bounds__(64) void merge_kernel(
    const float* __restrict__ ws, float* __restrict__ out)
{
    int n = blockIdx.x;   // 0..399
    int p = blockIdx.y;   // 0..1
    int t = threadIdx.x;  // 0..63
    const float* part = ws + WS_PART;

    float4 q[8];
    float M = -1e30f;
    #pragma unroll
    for (int k = 0; k < 8; ++k) {
        int mbk = t + 64*k;
        q[k] = *(const float4*)&part[((size_t)(p*MB_PER_P + mbk)*NKP + n)*4];
        M = fmaxf(M, q[k].x);
    }
    #pragma unroll
    for (int off = 1; off < 64; off <<= 1) M = fmaxf(M, __shfl_xor(M, off));
    float S = 0.0f, U = 0.0f, V = 0.0f;
    #pragma unroll
    for (int k = 0; k < 8; ++k) {
        float w = __expf(q[k].x - M);
        S = fmaf(w, q[k].y, S);
        U = fmaf(w, q[k].z, U);
        V = fmaf(w, q[k].w, V);
    }
    #pragma unroll
    for (int off = 1; off < 64; off <<= 1) {
        S += __shfl_xor(S, off);
        U += __shfl_xor(U, off);
        V += __shfl_xor(V, off);
    }
    if (t == 0) {
        out[(p*NKP + n)*2 + 0] = U / S;
        out[(p*NKP + n)*2 + 1] = V / S;
    }
}

extern "C" void kernel_launch(void* const* d_in, const int* in_sizes, int n_in,
                              void* d_out, int out_size, void* d_ws, size_t ws_size,
                              hipStream_t stream)
{
    const float* ks      = (const float*)d_in[0];  // keypoint_scores [4,1,400]
    const float* kd      = (const float*)d_in[1];  // keypoint_desc  [4,64,400]
    const float* dd      = (const float*)d_in[2];  // desc_dense     [4,64,256,256]
    const int*   tgt_ids = (const int*)d_in[3];    // [2]
    const int*   src_ids = (const int*)d_in[4];    // [2]
    float* out = (float*)d_out;
    float* ws  = (float*)d_ws;

    prep_kernel <<<dim3(NPAD, NPAIR),     64, 0, stream>>>(ks, kd, tgt_ids, src_ids, ws, out);
    match_kernel<<<dim3(MB_PER_P, NPAIR), 256, 0, stream>>>(dd, src_ids, ws);
    merge_kernel<<<dim3(NKP, NPAIR),      64, 0, stream>>>(ws, out);
}

// Round 2
// 215.575 us; speedup vs baseline: 1.0703x; 1.0703x over previous
//
#include <hip/hip_runtime.h>
#include <math.h>

#define NPAIR  2
#define KDIM   64
#define NKP    400
#define NPADR  448           /* keypoints padded to 14*32 */
#define DSTR   14            /* double-strips of 32 rows */
#define HWPIX  65536
#define MREF   70.0f         /* fixed softmax reference: logits = 100*cos <= 100 */

/* ws layout (dwords):
   [0, AFRAG_DW)  : tgt A-fragments [p][d][rt][ks][hi/lo][lane][4dw], bf16 pairs
   [AFRAG_DW, ..) : partials [p][448][256] float2 {S, U_local}            */
#define AFRAG_DW (NPAIR*DSTR*2*2*2*256)   /* 57344 dwords */

using frag_ab = __attribute__((ext_vector_type(8))) short;   // 8 bf16
using f32x4   = __attribute__((ext_vector_type(4))) float;

__device__ __forceinline__ unsigned short f2bf(float f){
    unsigned u = __builtin_bit_cast(unsigned, f);
    u += 0x7fffu + ((u >> 16) & 1u);          // round-to-nearest-even
    return (unsigned short)(u >> 16);
}
__device__ __forceinline__ float bf2f(unsigned short h){
    unsigned u = ((unsigned)h) << 16;
    return __builtin_bit_cast(float, u);
}
/* butterfly sum over 16-lane row groups, pure VALU (DPP) */
__device__ __forceinline__ float red16(float v){
    v += __builtin_bit_cast(float, __builtin_amdgcn_update_dpp(0, __builtin_bit_cast(int, v), 0xB1,  0xF, 0xF, true)); // xor1
    v += __builtin_bit_cast(float, __builtin_amdgcn_update_dpp(0, __builtin_bit_cast(int, v), 0x4E,  0xF, 0xF, true)); // xor2
    v += __builtin_bit_cast(float, __builtin_amdgcn_update_dpp(0, __builtin_bit_cast(int, v), 0x141, 0xF, 0xF, true)); // half-mirror
    v += __builtin_bit_cast(float, __builtin_amdgcn_update_dpp(0, __builtin_bit_cast(int, v), 0x140, 0xF, 0xF, true)); // mirror
    return v;
}

/* normalize tgt desc, split to bf16 hi/lo, store in MFMA A-frag order */
__global__ __launch_bounds__(64) void prep_kernel(
    const float* __restrict__ ksc, const float* __restrict__ kd,
    const int* __restrict__ tgt_ids, const int* __restrict__ src_ids,
    unsigned* __restrict__ wsu, float* __restrict__ out)
{
    int d = blockIdx.x, p = blockIdx.y, l = threadIdx.x;
    int tgt = tgt_ids[p];
    __shared__ float inv_s[32];
    if (l < 32){
        int n = d*32 + l; float s = 0.f;
        if (n < NKP){
            for (int c = 0; c < KDIM; ++c){ float v = kd[(tgt*KDIM + c)*NKP + n]; s = fmaf(v, v, s); }
            inv_s[l] = 1.f / fmaxf(sqrtf(s), 1e-12f);
        } else inv_s[l] = 0.f;
    }
    __syncthreads();
    int cl = l & 15, g = l >> 4;
    for (int rt = 0; rt < 2; ++rt){
        int n = d*32 + rt*16 + cl;
        float inv = inv_s[rt*16 + cl];
        for (int ks = 0; ks < 2; ++ks){
            int k0 = ks*32 + g*8;
            unsigned hu[4], lu[4];
            #pragma unroll
            for (int j2 = 0; j2 < 4; ++j2){
                float xa = 0.f, xb = 0.f;
                if (n < NKP){
                    xa = kd[(tgt*KDIM + k0 + 2*j2    )*NKP + n] * inv;
                    xb = kd[(tgt*KDIM + k0 + 2*j2 + 1)*NKP + n] * inv;
                }
                unsigned short ha = f2bf(xa), hb = f2bf(xb);
                unsigned short la = f2bf(xa - bf2f(ha)), lb = f2bf(xb - bf2f(hb));
                hu[j2] = (unsigned)ha | ((unsigned)hb << 16);
                lu[j2] = (unsigned)la | ((unsigned)lb << 16);
            }
            unsigned base = (unsigned)((((p*DSTR + d)*2 + rt)*2 + ks)*2)*256 + l*4;
            *(uint4*)&wsu[base]       = make_uint4(hu[0], hu[1], hu[2], hu[3]);
            *(uint4*)&wsu[base + 256] = make_uint4(lu[0], lu[1], lu[2], lu[3]);
        }
    }
    if (l < 32){
        int n = d*32 + l;
        if (n < NKP) out[NPAIR*NKP*2 + p*NKP + n] = ksc[tgt*NKP + n];
    }
    if (d == 0 && l == 0){
        out[NPAIR*NKP*3 + p]         = (float)tgt;
        out[NPAIR*NKP*3 + NPAIR + p] = (float)src_ids[p];
    }
}

/* one block per (pair, image row of 256 px): stage src hi/lo bf16 in LDS,
   barrier-free split-bf16 MFMA loop over 14 double-strips of keypoints,
   fixed-ref softmax partials out. */
__global__ __launch_bounds__(256, 2) void match_kernel(
    const float* __restrict__ dd, const int* __restrict__ src_ids,
    const unsigned* __restrict__ wsu, float* __restrict__ part)
{
    __shared__ unsigned lds[16384];   // hi plane [0,8192) dw, lo plane [8192,16384)
    int mb = blockIdx.x, p = blockIdx.y, t = threadIdx.x;
    const float* plane = dd + (size_t)src_ids[p]*KDIM*HWPIX + mb*256;

    /* staging: thread t owns pixel column m=t; coalesced fp32 loads,
       norm (x100 temp folded), split, swizzled b128 LDS writes */
    {
        int m = t;
        float x[64];
        #pragma unroll
        for (int k = 0; k < KDIM; ++k) x[k] = plane[(size_t)k*HWPIX + m];
        float ssum = 0.f;
        #pragma unroll
        for (int k = 0; k < KDIM; ++k) ssum = fmaf(x[k], x[k], ssum);
        float inv = 100.f / fmaxf(sqrtf(ssum), 1e-12f);
        unsigned hiD[32], loD[32];
        #pragma unroll
        for (int q = 0; q < 32; ++q){
            float a = x[2*q]*inv, b = x[2*q+1]*inv;
            unsigned short ha = f2bf(a), hb = f2bf(b);
            unsigned short la = f2bf(a - bf2f(ha)), lb = f2bf(b - bf2f(hb));
            hiD[q] = (unsigned)ha | ((unsigned)hb << 16);
            loD[q] = (unsigned)la | ((unsigned)lb << 16);
        }
        unsigned sw7 = (unsigned)(m & 7) << 2;
        #pragma unroll
        for (int s2 = 0; s2 < 8; ++s2){
            unsigned dwb = (unsigned)m*32 + (((unsigned)s2 << 2) ^ sw7);
            *(uint4*)&lds[dwb]        = make_uint4(hiD[4*s2], hiD[4*s2+1], hiD[4*s2+2], hiD[4*s2+3]);
            *(uint4*)&lds[8192 + dwb] = make_uint4(loD[4*s2], loD[4*s2+1], loD[4*s2+2], loD[4*s2+3]);
        }
    }
    __syncthreads();   // only barrier; main loop is barrier-free

    int w = t >> 6, l = t & 63;
    int cl = l & 15, g = l >> 4;
    for (int d = w; d < DSTR; d += 4){
        uint4 AH[2][2], AL[2][2];
        #pragma unroll
        for (int rt = 0; rt < 2; ++rt)
        #pragma unroll
        for (int ks = 0; ks < 2; ++ks){
            unsigned base = (unsigned)((((p*DSTR + d)*2 + rt)*2 + ks)*2)*256 + l*4;
            AH[rt][ks] = *(const uint4*)&wsu[base];
            AL[rt][ks] = *(const uint4*)&wsu[base + 256];
        }
        f32x4 acc[2][16];
        #pragma unroll
        for (int rt = 0; rt < 2; ++rt)
            #pragma unroll
            for (int mt = 0; mt < 16; ++mt)
                acc[rt][mt] = (f32x4){0.f, 0.f, 0.f, 0.f};

        #pragma unroll
        for (int mt = 0; mt < 16; ++mt){
            int mrow = mt*16 + cl;
            unsigned swm = (unsigned)(mrow & 7) << 2;
            #pragma unroll
            for (int ks = 0; ks < 2; ++ks){
                unsigned dwb = (unsigned)mrow*32 + (((unsigned)(ks*4 + g) << 2) ^ swm);
                frag_ab BH = __builtin_bit_cast(frag_ab, *(const uint4*)&lds[dwb]);
                frag_ab BL = __builtin_bit_cast(frag_ab, *(const uint4*)&lds[8192 + dwb]);
                frag_ab aH0 = __builtin_bit_cast(frag_ab, AH[0][ks]);
                frag_ab aH1 = __builtin_bit_cast(frag_ab, AH[1][ks]);
                frag_ab aL0 = __builtin_bit_cast(frag_ab, AL[0][ks]);
                frag_ab aL1 = __builtin_bit_cast(frag_ab, AL[1][ks]);
                acc[0][mt] = __builtin_amdgcn_mfma_f32_16x16x32_bf16(aH0, BH, acc[0][mt], 0, 0, 0);
                acc[1][mt] = __builtin_amdgcn_mfma_f32_16x16x32_bf16(aH1, BH, acc[1][mt], 0, 0, 0);
                acc[0][mt] = __builtin_amdgcn_mfma_f32_16x16x32_bf16(aH0, BL, acc[0][mt], 0, 0, 0);
                acc[1][mt] = __builtin_amdgcn_mfma_f32_16x16x32_bf16(aH1, BL, acc[1][mt], 0, 0, 0);
                acc[0][mt] = __builtin_amdgcn_mfma_f32_16x16x32_bf16(aL0, BH, acc[0][mt], 0, 0, 0);
                acc[1][mt] = __builtin_amdgcn_mfma_f32_16x16x32_bf16(aL1, BH, acc[1][mt], 0, 0, 0);
            }
        }
        /* fixed-ref softmax partials: S = sum e, U = sum e*u_local */
        #pragma unroll
        for (int rt = 0; rt < 2; ++rt)
        #pragma unroll
        for (int r = 0; r < 4; ++r){
            float sE = 0.f, sU = 0.f;
            #pragma unroll
            for (int mt = 0; mt < 16; ++mt){
                float e = __expf(acc[rt][mt][r] - MREF);
                sE += e;
                sU = fmaf(e, (float)(mt*16), sU);
            }
            sU = fmaf((float)cl, sE, sU);
            sE = red16(sE); sU = red16(sU);
            if (cl == 0){
                int n = d*32 + rt*16 + g*4 + r;
                *(float2*)&part[((size_t)(p*NPADR + n)*256 + mb)*2] = make_float2(sE, sU);
            }
        }
    }
}

/* one wave per (p,n): coalesced float4 partial reads, pure sum (fixed ref) */
__global__ __launch_bounds__(256) void merge_kernel(
    const float* __restrict__ part, float* __restrict__ out)
{
    int wid = blockIdx.x*4 + (threadIdx.x >> 6);   // 0..799
    int l = threadIdx.x & 63;
    int p = wid / NKP, n = wid - p*NKP;
    const float* base = part + (size_t)(p*NPADR + n)*512;
    float4 q0 = *(const float4*)&base[4*l];          // mb = 2l, 2l+1
    float4 q1 = *(const float4*)&base[256 + 4*l];    // mb = 128+2l, 129+2l
    float S = q0.x + q0.z + q1.x + q1.z;
    float U = q0.y + q0.w + q1.y + q1.w;
    float V = (float)(2*l)*q0.x + (float)(2*l+1)*q0.z
            + (float)(128+2*l)*q1.x + (float)(129+2*l)*q1.z;
    #pragma unroll
    for (int off = 1; off < 64; off <<= 1){
        S += __shfl_xor(S, off);
        U += __shfl_xor(U, off);
        V += __shfl_xor(V, off);
    }
    if (l == 0){
        out[(p*NKP + n)*2 + 0] = U / S;
        out[(p*NKP + n)*2 + 1] = V / S;
    }
}

extern "C" void kernel_launch(void* const* d_in, const int* in_sizes, int n_in,
                              void* d_out, int out_size, void* d_ws, size_t ws_size,
                              hipStream_t stream)
{
    const float* ksc     = (const float*)d_in[0];  // keypoint_scores [4,1,400]
    const float* kd      = (const float*)d_in[1];  // keypoint_desc  [4,64,400]
    const float* dd      = (const float*)d_in[2];  // desc_dense     [4,64,256,256]
    const int*   tgt_ids = (const int*)d_in[3];
    const int*   src_ids = (const int*)d_in[4];
    float* out = (float*)d_out;
    unsigned* wsu = (unsigned*)d_ws;
    float* part = (float*)d_ws + AFRAG_DW;

    prep_kernel <<<dim3(DSTR, NPAIR), 64,  0, stream>>>(ksc, kd, tgt_ids, src_ids, wsu, out);
    match_kernel<<<dim3(256,  NPAIR), 256, 0, stream>>>(dd, src_ids, wsu, part);
    merge_kernel<<<200,               256, 0, stream>>>(part, out);
}